// Round 5
// baseline (92.975 us; speedup 1.0000x reference)
//
#include <hip/hip_runtime.h>

#define DROWS 4096
#define NCOLS 8192

// ---- ordered-uint encoding so unsigned atomicMin/Max == float min/max ----
__device__ __forceinline__ unsigned encf(float f) {
    unsigned u = __float_as_uint(f);
    return (u & 0x80000000u) ? ~u : (u | 0x80000000u);
}
__device__ __forceinline__ float decf(unsigned u) {
    unsigned v = (u & 0x80000000u) ? (u ^ 0x80000000u) : ~u;
    return __uint_as_float(v);
}

__global__ __launch_bounds__(256) void init_minmax(unsigned* __restrict__ mine,
                                                   unsigned* __restrict__ maxe) {
    int i = blockIdx.x * 256 + threadIdx.x;
    mine[i] = 0xFFFFFFFFu;  // encoded +inf-ish (largest key)
    maxe[i] = 0u;           // smallest key
}

// Per-column min/max. grid = (8, 64): blockIdx.x tiles 1024 columns (256 thr * 4),
// blockIdx.y tiles 64 rows. Coalesced float4 loads; 8 atomics per thread at the end.
__global__ __launch_bounds__(256) void colminmax(const float* __restrict__ x,
                                                 unsigned* __restrict__ mine,
                                                 unsigned* __restrict__ maxe) {
    int c = blockIdx.x * 1024 + threadIdx.x * 4;
    int r0 = blockIdx.y * 64;
    const float* p = x + (size_t)r0 * NCOLS + c;

    float4 mn = *(const float4*)p;
    float4 mx = mn;
#pragma unroll 8
    for (int i = 1; i < 64; ++i) {
        float4 v = *(const float4*)(p + (size_t)i * NCOLS);
        mn.x = fminf(mn.x, v.x); mn.y = fminf(mn.y, v.y);
        mn.z = fminf(mn.z, v.z); mn.w = fminf(mn.w, v.w);
        mx.x = fmaxf(mx.x, v.x); mx.y = fmaxf(mx.y, v.y);
        mx.z = fmaxf(mx.z, v.z); mx.w = fmaxf(mx.w, v.w);
    }
    atomicMin(&mine[c + 0], encf(mn.x));
    atomicMin(&mine[c + 1], encf(mn.y));
    atomicMin(&mine[c + 2], encf(mn.z));
    atomicMin(&mine[c + 3], encf(mn.w));
    atomicMax(&maxe[c + 0], encf(mx.x));
    atomicMax(&maxe[c + 1], encf(mx.y));
    atomicMax(&maxe[c + 2], encf(mx.z));
    atomicMax(&maxe[c + 3], encf(mx.w));
}

__global__ __launch_bounds__(256) void finalize_minmax(const unsigned* __restrict__ mine,
                                                       const unsigned* __restrict__ maxe,
                                                       float* __restrict__ fmin,
                                                       float* __restrict__ fsr) {
    int i = blockIdx.x * 256 + threadIdx.x;
    float mn = decf(mine[i]);
    float mx = decf(maxe[i]);
    float r = mx - mn;
    fmin[i] = mn;
    fsr[i] = (r == 0.0f) ? 1.0f : r;  // sklearn _handle_zeros_in_scale
}

__device__ __forceinline__ float block_sum(float v, float* red) {
#pragma unroll
    for (int m = 32; m; m >>= 1) v += __shfl_xor(v, m, 64);
    int wid = threadIdx.x >> 6;
    int lane = threadIdx.x & 63;
    __syncthreads();             // protect red[] from previous round's readers
    if (lane == 0) red[wid] = v;
    __syncthreads();
    return red[0] + red[1] + red[2] + red[3];
}

// One block per row. Row (8192 f32) lives in registers: 8 x float4 per thread.
// 10 iterations fully in-register; one fused block-sum per iteration.
__global__ __launch_bounds__(256) void rowiter(const float* __restrict__ x,
                                               const float* __restrict__ fmin,
                                               const float* __restrict__ fsr,
                                               float* __restrict__ out) {
    int row = blockIdx.x;
    int t = threadIdx.x;
    const float* xr = x + (size_t)row * NCOLS;
    float* outr = out + (size_t)row * NCOLS;

    __shared__ float red[4];

    float4 arr[8];
    float psum = 0.0f;
#pragma unroll
    for (int k = 0; k < 8; ++k) {
        int c = k * 1024 + t * 4;
        float4 v = *(const float4*)(xr + c);
        float4 mn = *(const float4*)(fmin + c);
        float4 sr = *(const float4*)(fsr + c);
        float4 a;
        a.x = (v.x - mn.x) / sr.x;
        a.y = (v.y - mn.y) / sr.y;
        a.z = (v.z - mn.z) / sr.z;
        a.w = (v.w - mn.w) / sr.w;
        arr[k] = a;
        psum += (a.x + a.y) + (a.z + a.w);
    }
    float sum = block_sum(psum, red);

#pragma unroll
    for (int it = 0; it < 10; ++it) {
        float mean = sum * (1.0f / 8192.0f);  // exact pow-2: identical to /8192
        float add = (it == 0) ? 0.001f : 0.0f;
        psum = 0.0f;
#pragma unroll
        for (int k = 0; k < 8; ++k) {
            float4 a = arr[k];
            a.x = a.x * (1.0f - (a.x - mean)) + add;
            a.y = a.y * (1.0f - (a.y - mean)) + add;
            a.z = a.z * (1.0f - (a.z - mean)) + add;
            a.w = a.w * (1.0f - (a.w - mean)) + add;
            arr[k] = a;
            psum += (a.x + a.y) + (a.z + a.w);
        }
        if (it < 9) sum = block_sum(psum, red);  // uniform condition: barrier-safe
    }

#pragma unroll
    for (int k = 0; k < 8; ++k) {
        int c = k * 1024 + t * 4;
        float4 mn = *(const float4*)(fmin + c);
        float4 sr = *(const float4*)(fsr + c);
        float4 a = arr[k];
        float4 o;
        o.x = fmaf(a.x, sr.x, mn.x);
        o.y = fmaf(a.y, sr.y, mn.y);
        o.z = fmaf(a.z, sr.z, mn.z);
        o.w = fmaf(a.w, sr.w, mn.w);
        *(float4*)(outr + c) = o;
    }
}

extern "C" void kernel_launch(void* const* d_in, const int* in_sizes, int n_in,
                              void* d_out, int out_size, void* d_ws, size_t ws_size,
                              hipStream_t stream) {
    const float* x = (const float*)d_in[0];
    float* out = (float*)d_out;

    // ws layout: mine[8192] u32 | maxe[8192] u32 | fmin[8192] f32 | fsr[8192] f32 = 128 KiB
    unsigned* mine = (unsigned*)d_ws;
    unsigned* maxe = mine + NCOLS;
    float* fmin = (float*)(maxe + NCOLS);
    float* fsr = fmin + NCOLS;

    init_minmax<<<NCOLS / 256, 256, 0, stream>>>(mine, maxe);
    colminmax<<<dim3(NCOLS / 1024, DROWS / 64), 256, 0, stream>>>(x, mine, maxe);
    finalize_minmax<<<NCOLS / 256, 256, 0, stream>>>(mine, maxe, fmin, fsr);
    rowiter<<<DROWS, 256, 0, stream>>>(x, fmin, fsr, out);
}